// Round 5
// baseline (2774.112 us; speedup 1.0000x reference)
//
#include <hip/hip_runtime.h>

// Problem constants (GCN_61065845014917)
#define B_   4
#define C_   1024
#define D_   768
#define H_   12
#define E_   32
#define K_   2
#define S_   24
#define V_   8
#define P_   512
#define NT_  256
#define EMB_ 768
#define BLK_ 64
#define NL_  97
#define DNT_ 1024     // D+NT
#define KHT_ 1792     // 2D+NT
#define KBIL_ 49152   // EMB*BLK
#define NPAD_ 128     // NL padded for MFMA

typedef __bf16 bf16x8 __attribute__((ext_vector_type(8)));
typedef float  f32x4  __attribute__((ext_vector_type(4)));

__device__ __forceinline__ float b2f(unsigned short u) {
    return (float)__builtin_bit_cast(__bf16, u);
}
__device__ __forceinline__ unsigned short f2b(float f) {
    return __builtin_bit_cast(unsigned short, (__bf16)f);   // RNE
}
// dtype-dispatched input load / output store (isf=1: f32 buffers, isf=0: bf16)
__device__ __forceinline__ float ld_in(const void* p, size_t i, int isf) {
    return isf ? ((const float*)p)[i] : b2f(((const unsigned short*)p)[i]);
}
__device__ __forceinline__ void st_out(void* p, size_t i, float v, int isf) {
    if (isf) ((float*)p)[i] = v;
    else     ((unsigned short*)p)[i] = f2b(v);
}
// per-wave inline dtype probe: 64 even-index ushorts of sequence_output.
// f32 data -> low mantissa halves: random (huge/NaN bf16 patterns, P(miss)<1e-13)
// or all-zero (f32 upcast of bf16-grained values). bf16 data -> small, nonzero.
__device__ __forceinline__ int probe_isf(const void* seq) {
    unsigned short u = ((const unsigned short*)seq)[2 * (threadIdx.x & 63)];
    int huge = !(fabsf(b2f(u)) <= 1e10f);          // catches NaN
    unsigned long long zb = __ballot(u == 0);
    return __any(huge) || (__popcll(zb) > 56);
}

// ---------------------------------------------------------------------------
// K1 fused prep: [0,256) gather, [256,1792) eatt, [1792,2560) t_seq,
//                [2560,3232) t_w, [3232,4000) t_bil(64k/blk)
#define PREP_GATHER 256
#define PREP_EATT   (PREP_GATHER + B_*E_*H_)     // +1536 -> 1792
#define PREP_TSEQ   (PREP_EATT + 768)            // -> 2560
#define PREP_TW     (PREP_TSEQ + 672)            // -> 3232
#define PREP_TBIL   (PREP_TW + 768)              // -> 4000

__global__ __launch_bounds__(256) void k_prep(
    const void* __restrict__ seq, const void* __restrict__ att,
    const int* __restrict__ epos, const int* __restrict__ spos,
    const int* __restrict__ vpos, const void* __restrict__ ntype,
    const void* __restrict__ Wh, const void* __restrict__ Wt_,
    const void* __restrict__ Wb,
    float* __restrict__ enth, unsigned short* __restrict__ e_att,
    unsigned short* __restrict__ seqT,
    unsigned short* __restrict__ WtH, unsigned short* __restrict__ WtT,
    unsigned short* __restrict__ WtB,
    void* __restrict__ outv, long long moff, long long soff, long long voff)
{
    __shared__ __align__(16) unsigned char smem[12544];
    int blk = blockIdx.x, tid = threadIdx.x;
    int isf = probe_isf(seq);
    if (blk < PREP_GATHER) {
        if (blk < B_ * E_) {
            int b = blk / E_, e = blk % E_;
            int i0 = epos[(b * E_ + e) * K_ + 0] + 1;
            int i1 = epos[(b * E_ + e) * K_ + 1] + 1;
            size_t r0 = ((size_t)b * C_ + i0) * D_;
            size_t r1 = ((size_t)b * C_ + i1) * D_;
            size_t m0 = (size_t)moff + ((size_t)(b * E_ * K_) + 2 * e) * D_;
            size_t m1 = m0 + D_;
            float* eh = enth + (size_t)(b * E_ + e) * DNT_;
            for (int d = tid; d < D_; d += 256) {
                float a = ld_in(seq, r0 + d, isf);
                float c = ld_in(seq, r1 + d, isf);
                st_out(outv, m0 + d, a, isf);
                st_out(outv, m1 + d, c, isf);
                float mx = fmaxf(a, c);
                eh[d] = mx + logf(expf(a - mx) + expf(c - mx));
            }
            size_t nt0 = (size_t)(b * E_ + e) * NT_;
            for (int j = tid; j < NT_; j += 256) eh[D_ + j] = ld_in(ntype, nt0 + j, isf);
        } else if (blk < B_ * E_ + B_ * S_) {
            int t = blk - B_ * E_; int b = t / S_, s = t % S_;
            int i = spos[b * S_ + s] + 1;
            size_t r = ((size_t)b * C_ + i) * D_;
            size_t o = (size_t)soff + (size_t)(b * S_ + s) * D_;
            for (int d = tid; d < D_; d += 256) st_out(outv, o + d, ld_in(seq, r + d, isf), isf);
        } else {
            int t = blk - B_ * E_ - B_ * S_; int b = t / V_, v = t % V_;
            int i = vpos[b * V_ + v] + 1;
            size_t r = ((size_t)b * C_ + i) * D_;
            size_t o = (size_t)voff + (size_t)(b * V_ + v) * D_;
            for (int d = tid; d < D_; d += 256) st_out(outv, o + d, ld_in(seq, r + d, isf), isf);
        }
    } else if (blk < PREP_EATT) {
        int t = blk - PREP_GATHER;
        int b = t / (E_ * H_); int r = t % (E_ * H_); int e = r / H_; int h = r % H_;
        int i0 = epos[(b * E_ + e) * K_ + 0] + 1;
        int i1 = epos[(b * E_ + e) * K_ + 1] + 1;
        size_t a0 = (((size_t)b * H_ + h) * C_ + i0) * C_;
        size_t a1 = (((size_t)b * H_ + h) * C_ + i1) * C_;
        unsigned short* o = e_att + (((size_t)(b * E_ + e)) * H_ + h) * C_;
        for (int c = tid; c < C_; c += 256)
            o[c] = f2b(0.5f * (ld_in(att, a0 + c, isf) + ld_in(att, a1 + c, isf)));
    } else if (blk < PREP_TSEQ) {
        int t = blk - PREP_EATT;                 // b*192 + ct*12 + dt
        int b = t / 192; int r = t % 192; int ct = r / 12; int dt = r % 12;
        typedef unsigned short row65[65];
        row65* tile = (row65*)smem;
        for (int idx = tid; idx < 4096; idx += 256) {
            int cc = idx >> 6, dd = idx & 63;
            tile[cc][dd] = f2b(ld_in(seq, ((size_t)b * C_ + ct * 64 + cc) * D_ + dt * 64 + dd, isf));
        }
        __syncthreads();
        for (int idx = tid; idx < 4096; idx += 256) {
            int dd = idx >> 6, cc = idx & 63;
            seqT[((size_t)b * D_ + dt * 64 + dd) * C_ + ct * 64 + cc] = tile[cc][dd];
        }
    } else if (blk < PREP_TW) {
        int t = blk - PREP_TSEQ;                 // mat*336 + kt*12 + nt
        int mat = t / 336; int r = t % 336; int kt = r / 12; int nt = r % 12;
        const void* in = mat ? Wt_ : Wh;
        unsigned short* out = mat ? WtT : WtH;
        typedef unsigned short row65[65];
        row65* tile = (row65*)smem;
        for (int idx = tid; idx < 4096; idx += 256) {
            int kk = idx >> 6, nn = idx & 63;
            tile[kk][nn] = f2b(ld_in(in, ((size_t)kt * 64 + kk) * EMB_ + nt * 64 + nn, isf));
        }
        __syncthreads();
        for (int idx = tid; idx < 4096; idx += 256) {
            int nn = idx >> 6, kk = idx & 63;
            out[((size_t)nt * 64 + nn) * KHT_ + kt * 64 + kk] = tile[kk][nn];
        }
    } else {
        int t = blk - PREP_TW;                   // 64 k-cols per block
        int k0 = t << 6;
        unsigned short* raw = (unsigned short*)smem;   // [64*97]
        for (int idx = tid; idx < 64 * NL_; idx += 256)
            raw[idx] = f2b(ld_in(Wb, (size_t)k0 * NL_ + idx, isf));
        __syncthreads();
        int kk = tid & 63, nq = tid >> 6;              // 4 quarters x 32 n
        for (int i = 0; i < 32; i++) {
            int n = nq * 32 + i;
            unsigned short v = (n < NL_) ? raw[kk * NL_ + n] : (unsigned short)0;
            WtB[(size_t)n * KBIL_ + k0 + kk] = v;
        }
    }
}

// ---------------------------------------------------------------------------
// K2 fused mid: [0,2048) htatt, [2048,4096) xbuild, [4096,4352) zero logitsF
__global__ __launch_bounds__(256) void k_mid(
    const unsigned short* __restrict__ e_att, const float* __restrict__ enth,
    const int* __restrict__ hts,
    unsigned short* __restrict__ htb,
    unsigned short* __restrict__ Xh, unsigned short* __restrict__ Xt,
    float* __restrict__ logitsF)
{
    __shared__ float red[4];
    int blk = blockIdx.x, tid = threadIdx.x;
    if (blk < B_ * P_) {
        int b = blk >> 9;
        int he = hts[blk * 2 + 0], te = hts[blk * 2 + 1];
        const unsigned short* ph = e_att + (size_t)(b * E_ + he) * H_ * C_;
        const unsigned short* pt = e_att + (size_t)(b * E_ + te) * H_ * C_;
        float v[4]; float ls = 0.f;
        for (int ci = 0; ci < 4; ci++) {
            int c = tid + (ci << 8);
            float acc = 0.f;
#pragma unroll
            for (int h = 0; h < H_; h++) acc += b2f(ph[h * C_ + c]) * b2f(pt[h * C_ + c]);
            acc *= (1.0f / (float)H_);
            v[ci] = acc; ls += acc;
        }
        for (int off = 32; off > 0; off >>= 1) ls += __shfl_down(ls, off, 64);
        if ((tid & 63) == 0) red[tid >> 6] = ls;
        __syncthreads();
        float inv = 1.0f / (red[0] + red[1] + red[2] + red[3] + 1e-5f);
        for (int ci = 0; ci < 4; ci++)
            htb[((size_t)blk << 10) + tid + (ci << 8)] = f2b(v[ci] * inv);
    } else if (blk < 2 * B_ * P_) {
        int m = blk - B_ * P_; int b = m >> 9;
        int eh = hts[m * 2 + 0], et = hts[m * 2 + 1];
        const float* sh = enth + (size_t)(b * E_ + eh) * DNT_;
        const float* st = enth + (size_t)(b * E_ + et) * DNT_;
        for (int k = tid; k < DNT_; k += 256) {
            Xh[(size_t)m * KHT_ + k] = f2b(sh[k]);
            Xt[(size_t)m * KHT_ + k] = f2b(st[k]);
        }
    } else {
        int t = blk - 2 * B_ * P_;               // 256 blocks zero 1 MB
        ((float4*)logitsF)[(size_t)t * 256 + tid] = make_float4(0.f, 0.f, 0.f, 0.f);
    }
}

// ---------------------------------------------------------------------------
// LDS-free streaming MFMA GEMM. One wave owns a 32x32 output tile; A/B
// fragments read straight from L2-resident row-major [rows][K] buffers
// (16 B/lane), depth-4 register prefetch, NO __syncthreads, NO LDS.
// zmode 0 (rs): z = batch; epilogue writes bf16 into Xh/Xt cols DNT_+n.
// zmode 1 (ht): z = mat (0=head,1=tail); epilogue bf16 tanh(acc+bias) -> oY.
__global__ __launch_bounds__(256) void k_sgemm(
    const unsigned short* __restrict__ A0, const unsigned short* __restrict__ A1,
    const unsigned short* __restrict__ B0, const unsigned short* __restrict__ B1,
    long long lda, long long ldb, long long sAz, long long sBz,
    int nsteps, int ntiles, int zmode,
    const void* __restrict__ bias0, const void* __restrict__ bias1,
    unsigned short* __restrict__ oY0, unsigned short* __restrict__ oY1,
    unsigned short* __restrict__ oX1, unsigned short* __restrict__ oX2,
    const void* __restrict__ seq)
{
    int z = blockIdx.z;
    const unsigned short* Ab; const unsigned short* Bb;
    unsigned short* oY = nullptr; const void* bias = nullptr;
    if (zmode == 0) {
        Ab = A0 + (size_t)z * sAz; Bb = B0 + (size_t)z * sBz;
    } else {
        Ab = z ? A1 : A0; Bb = z ? B1 : B0;
        oY = z ? oY1 : oY0; bias = z ? bias1 : bias0;
    }
    int tid = threadIdx.x, lane = tid & 63, w = tid >> 6;
    int q = lane >> 4, l15 = lane & 15;
    int wid = blockIdx.x * 4 + w;
    int mt = wid / ntiles, nt = wid % ntiles;

    const unsigned short* pa0 = Ab + (size_t)(mt * 32 + l15) * lda + q * 8;
    const unsigned short* pa1 = pa0 + (size_t)16 * lda;
    const unsigned short* pb0 = Bb + (size_t)(nt * 32 + l15) * ldb + q * 8;
    const unsigned short* pb1 = pb0 + (size_t)16 * ldb;

    f32x4 acc00 = {0.f,0.f,0.f,0.f}, acc01 = acc00, acc10 = acc00, acc11 = acc00;
    bf16x8 fa0[4], fa1[4], fb0[4], fb1[4];
#pragma unroll
    for (int d = 0; d < 4; d++) {
        fa0[d] = *(const bf16x8*)(pa0 + (size_t)d * 32);
        fa1[d] = *(const bf16x8*)(pa1 + (size_t)d * 32);
        fb0[d] = *(const bf16x8*)(pb0 + (size_t)d * 32);
        fb1[d] = *(const bf16x8*)(pb1 + (size_t)d * 32);
    }
#pragma unroll 4
    for (int ks = 0; ks < nsteps; ks++) {
        int sl = ks & 3;
        bf16x8 a0 = fa0[sl], a1 = fa1[sl], b0 = fb0[sl], b1 = fb1[sl];
        if (ks + 4 < nsteps) {
            fa0[sl] = *(const bf16x8*)(pa0 + (size_t)(ks + 4) * 32);
            fa1[sl] = *(const bf16x8*)(pa1 + (size_t)(ks + 4) * 32);
            fb0[sl] = *(const bf16x8*)(pb0 + (size_t)(ks + 4) * 32);
            fb1[sl] = *(const bf16x8*)(pb1 + (size_t)(ks + 4) * 32);
        }
        acc00 = __builtin_amdgcn_mfma_f32_16x16x32_bf16(a0, b0, acc00, 0, 0, 0);
        acc01 = __builtin_amdgcn_mfma_f32_16x16x32_bf16(a0, b1, acc01, 0, 0, 0);
        acc10 = __builtin_amdgcn_mfma_f32_16x16x32_bf16(a1, b0, acc10, 0, 0, 0);
        acc11 = __builtin_amdgcn_mfma_f32_16x16x32_bf16(a1, b1, acc11, 0, 0, 0);
    }
    f32x4 accs[2][2] = {{acc00, acc01}, {acc10, acc11}};
    int isf = (zmode == 1) ? probe_isf(seq) : 0;
#pragma unroll
    for (int mti = 0; mti < 2; mti++)
#pragma unroll
        for (int nti = 0; nti < 2; nti++) {
            int gmb = mt * 32 + mti * 16 + q * 4;
            int gn  = nt * 32 + nti * 16 + l15;
            if (zmode == 0) {
#pragma unroll
                for (int r = 0; r < 4; r++) {
                    unsigned short v = f2b(accs[mti][nti][r]);
                    size_t o = (size_t)(z * P_ + gmb + r) * KHT_ + DNT_ + gn;
                    oX1[o] = v; oX2[o] = v;
                }
            } else {
                float bv = ld_in(bias, gn, isf);
#pragma unroll
                for (int r = 0; r < 4; r++)
                    oY[(size_t)(gmb + r) * EMB_ + gn] = f2b(tanhf(accs[mti][nti][r] + bv));
            }
        }
}

// ---------------------------------------------------------------------------
// Grouped bilinear via MFMA, K split over groups (grid.y = g), atomic f32 acc.
// hs/ts arrive pre-tanh'd in bf16. Depth-2 B-fragment prefetch.
__global__ __launch_bounds__(256) void k_bil(
    const unsigned short* __restrict__ hsB, const unsigned short* __restrict__ tsB,
    const unsigned short* __restrict__ WtB, float* __restrict__ logitsF)
{
    int m0 = blockIdx.x * 32;
    int g  = blockIdx.y;
    int tid = threadIdx.x, lane = tid & 63, w = tid >> 6;
    int q = lane >> 4, l15 = lane & 15;
    __shared__ __align__(16) unsigned short hsl[32][80];   // 160 B rows (16B-aligned)
    __shared__ __align__(16) unsigned short tsl[32][80];
    for (int idx = tid; idx < 512; idx += 256) {
        int m = idx >> 4, j4 = (idx & 15) * 4;
        *(ushort4*)&hsl[m][j4] = *(const ushort4*)&hsB[(size_t)(m0 + m) * EMB_ + g * 64 + j4];
        *(ushort4*)&tsl[m][j4] = *(const ushort4*)&tsB[(size_t)(m0 + m) * EMB_ + g * 64 + j4];
    }
    __syncthreads();

    const unsigned short* pB0 = WtB + (size_t)(w * 16 + l15) * KBIL_ + g * 4096 + q * 8;
    const unsigned short* pB1 = pB0 + (size_t)64 * KBIL_;
    bf16x8 rb0[2], rb1[2];
    rb0[0] = *(const bf16x8*)(pB0);      rb1[0] = *(const bf16x8*)(pB1);
    rb0[1] = *(const bf16x8*)(pB0 + 32); rb1[1] = *(const bf16x8*)(pB1 + 32);
    f32x4 acc00 = {0.f,0.f,0.f,0.f}, acc01 = acc00, acc10 = acc00, acc11 = acc00;

#pragma unroll 2
    for (int kk = 0; kk < 128; kk++) {
        int sl = kk & 1;
        bf16x8 bw0 = rb0[sl], bw1 = rb1[sl];
        if (kk + 2 < 128) {
            rb0[sl] = *(const bf16x8*)(pB0 + (size_t)(kk + 2) * 32);
            rb1[sl] = *(const bf16x8*)(pB1 + (size_t)(kk + 2) * 32);
        }
        int i = kk >> 1, h = kk & 1;
        float ha0 = b2f(hsl[l15][i]);
        float ha1 = b2f(hsl[16 + l15][i]);
        bf16x8 t0 = *(const bf16x8*)&tsl[l15][h * 32 + q * 8];
        bf16x8 t1 = *(const bf16x8*)&tsl[16 + l15][h * 32 + q * 8];
        bf16x8 af0, af1;
#pragma unroll
        for (int j = 0; j < 8; j++) {
            af0[j] = (__bf16)(ha0 * (float)t0[j]);
            af1[j] = (__bf16)(ha1 * (float)t1[j]);
        }
        acc00 = __builtin_amdgcn_mfma_f32_16x16x32_bf16(af0, bw0, acc00, 0, 0, 0);
        acc01 = __builtin_amdgcn_mfma_f32_16x16x32_bf16(af0, bw1, acc01, 0, 0, 0);
        acc10 = __builtin_amdgcn_mfma_f32_16x16x32_bf16(af1, bw0, acc10, 0, 0, 0);
        acc11 = __builtin_amdgcn_mfma_f32_16x16x32_bf16(af1, bw1, acc11, 0, 0, 0);
    }
#pragma unroll
    for (int r = 0; r < 4; r++) {
        atomicAdd(&logitsF[(size_t)(m0 + q * 4 + r) * NPAD_ + w * 16 + l15],           acc00[r]);
        atomicAdd(&logitsF[(size_t)(m0 + q * 4 + r) * NPAD_ + w * 16 + 64 + l15],      acc01[r]);
        atomicAdd(&logitsF[(size_t)(m0 + 16 + q * 4 + r) * NPAD_ + w * 16 + l15],      acc10[r]);
        atomicAdd(&logitsF[(size_t)(m0 + 16 + q * 4 + r) * NPAD_ + w * 16 + 64 + l15], acc11[r]);
    }
}

// ---------------------------------------------------------------------------
// final: logits out with bias, n<97
__global__ __launch_bounds__(256) void k_fin(
    const float* __restrict__ logitsF, const void* __restrict__ b_bil,
    void* __restrict__ outv, const void* __restrict__ seq)
{
    int isf = probe_isf(seq);
    int idx = blockIdx.x * 256 + threadIdx.x;
    if (idx >= B_ * P_ * NL_) return;
    int m = idx / NL_, n = idx % NL_;
    st_out(outv, idx, logitsF[(size_t)m * NPAD_ + n] + ld_in(b_bil, n, isf), isf);
}

// ---------------------------------------------------------------------------
extern "C" void kernel_launch(void* const* d_in, const int* in_sizes, int n_in,
                              void* d_out, int out_size, void* d_ws, size_t ws_size,
                              hipStream_t stream)
{
    const void* seq    = d_in[0];
    const void* att    = d_in[1];
    const int*  epos   = (const int*)d_in[2];
    const int*  spos   = (const int*)d_in[3];
    const int*  vpos   = (const int*)d_in[4];
    const int*  hts    = (const int*)d_in[5];
    const void* ntype  = d_in[6];
    const void* W_head = d_in[7];
    const void* b_head = d_in[8];
    const void* W_tail = d_in[9];
    const void* b_tail = d_in[10];
    const void* W_bil  = d_in[11];
    const void* b_bil  = d_in[12];

    // output element offsets (dtype-agnostic)
    long long mention_off = (long long)B_ * P_ * NL_;
    long long sent_off    = mention_off + (long long)B_ * E_ * K_ * D_;
    long long virt_off    = sent_off + (long long)B_ * S_ * D_;

    // workspace carve (~50 MB)
    char* p = (char*)d_ws;
    auto alloc = [&](size_t bytes) { void* r = (void*)p; p += (bytes + 255) & ~(size_t)255; return r; };
    unsigned short* e_att   = (unsigned short*)alloc((size_t)B_ * E_ * H_ * C_ * 2);
    unsigned short* htb     = (unsigned short*)alloc((size_t)B_ * P_ * C_ * 2);
    unsigned short* seqT    = (unsigned short*)alloc((size_t)B_ * D_ * C_ * 2);
    unsigned short* WtH     = (unsigned short*)alloc((size_t)EMB_ * KHT_ * 2);
    unsigned short* WtT     = (unsigned short*)alloc((size_t)EMB_ * KHT_ * 2);
    unsigned short* WtB     = (unsigned short*)alloc((size_t)NPAD_ * KBIL_ * 2);
    unsigned short* Xh      = (unsigned short*)alloc((size_t)B_ * P_ * KHT_ * 2);
    unsigned short* Xt      = (unsigned short*)alloc((size_t)B_ * P_ * KHT_ * 2);
    unsigned short* hsB     = (unsigned short*)alloc((size_t)B_ * P_ * EMB_ * 2);
    unsigned short* tsB     = (unsigned short*)alloc((size_t)B_ * P_ * EMB_ * 2);
    float*          logitsF = (float*)alloc((size_t)B_ * P_ * NPAD_ * 4);
    float*          enth    = (float*)alloc((size_t)B_ * E_ * DNT_ * 4);

    dim3 blk(256);
    k_prep<<<PREP_TBIL, blk, 0, stream>>>(
        seq, att, epos, spos, vpos, ntype, W_head, W_tail, W_bil,
        enth, e_att, seqT, WtH, WtT, WtB,
        d_out, mention_off, sent_off, virt_off);
    k_mid<<<2 * B_ * P_ + 256, blk, 0, stream>>>(e_att, enth, hts, htb, Xh, Xt, logitsF);
    // rs GEMM: per batch [512 x 1024] @ [1024 x 768]^T -> X cols 1024..1791
    // waves = 16 mt * 24 nt = 384 per z -> 96 blocks, z = 4
    k_sgemm<<<dim3(96, 1, B_), blk, 0, stream>>>(
        htb, nullptr, seqT, nullptr, C_, C_,
        (long long)P_ * C_, (long long)D_ * C_, C_ / 32, 24, 0,
        nullptr, nullptr, nullptr, nullptr, Xh, Xt, seq);
    // head/tail: [2048 x 1792] @ [1792 x 768]^T, tanh+bias -> bf16 hsB/tsB
    // waves = 64 mt * 24 nt = 1536 per z -> 384 blocks, z = 2
    k_sgemm<<<dim3(384, 1, 2), blk, 0, stream>>>(
        Xh, Xt, WtH, WtT, KHT_, KHT_, 0, 0, KHT_ / 32, 24, 1,
        b_head, b_tail, hsB, tsB, nullptr, nullptr, seq);
    k_bil<<<dim3((B_ * P_) / 32, 12, 1), blk, 0, stream>>>(hsB, tsB, WtB, logitsF);
    k_fin<<<(B_ * P_ * NL_ + 255) / 256, blk, 0, stream>>>(logitsF, b_bil, d_out, seq);
}

// Round 6
// 450.236 us; speedup vs baseline: 6.1615x; 6.1615x over previous
//
#include <hip/hip_runtime.h>

// Problem constants (GCN_61065845014917)
#define B_   4
#define C_   1024
#define D_   768
#define H_   12
#define E_   32
#define K_   2
#define S_   24
#define V_   8
#define P_   512
#define NT_  256
#define EMB_ 768
#define BLK_ 64
#define NL_  97
#define DNT_ 1024     // D+NT
#define KHT_ 1792     // 2D+NT
#define KBIL_ 49152   // EMB*BLK
#define NPAD_ 128     // NL padded for MFMA

typedef __bf16 bf16x8 __attribute__((ext_vector_type(8)));
typedef float  f32x4  __attribute__((ext_vector_type(4)));

__device__ __forceinline__ float b2f(unsigned short u) {
    return (float)__builtin_bit_cast(__bf16, u);
}
__device__ __forceinline__ unsigned short f2b(float f) {
    return __builtin_bit_cast(unsigned short, (__bf16)f);   // RNE
}
// dtype-dispatched input load / output store (isf=1: f32 buffers, isf=0: bf16)
__device__ __forceinline__ float ld_in(const void* p, size_t i, int isf) {
    return isf ? ((const float*)p)[i] : b2f(((const unsigned short*)p)[i]);
}
__device__ __forceinline__ void st_out(void* p, size_t i, float v, int isf) {
    if (isf) ((float*)p)[i] = v;
    else     ((unsigned short*)p)[i] = f2b(v);
}
// per-wave inline dtype probe: 64 even-index ushorts of sequence_output.
// f32 data -> low mantissa halves: random (huge/NaN bf16 patterns) or all-zero
// (f32 upcast of bf16-grained values). bf16 data -> small, nonzero.
__device__ __forceinline__ int probe_isf(const void* seq) {
    unsigned short u = ((const unsigned short*)seq)[2 * (threadIdx.x & 63)];
    int huge = !(fabsf(b2f(u)) <= 1e10f);          // catches NaN
    unsigned long long zb = __ballot(u == 0);
    return __any(huge) || (__popcll(zb) > 56);
}

// ---------------------------------------------------------------------------
// K1 fused prep: [0,256) gather, [256,1792) eatt, [1792,2560) t_seq,
//                [2560,3232) t_w, [3232,4000) t_bil(64k/blk)
#define PREP_GATHER 256
#define PREP_EATT   (PREP_GATHER + B_*E_*H_)     // +1536 -> 1792
#define PREP_TSEQ   (PREP_EATT + 768)            // -> 2560
#define PREP_TW     (PREP_TSEQ + 672)            // -> 3232
#define PREP_TBIL   (PREP_TW + 768)              // -> 4000

__global__ __launch_bounds__(256) void k_prep(
    const void* __restrict__ seq, const void* __restrict__ att,
    const int* __restrict__ epos, const int* __restrict__ spos,
    const int* __restrict__ vpos, const void* __restrict__ ntype,
    const void* __restrict__ Wh, const void* __restrict__ Wt_,
    const void* __restrict__ Wb,
    float* __restrict__ enth, unsigned short* __restrict__ e_att,
    unsigned short* __restrict__ seqT,
    unsigned short* __restrict__ WtH, unsigned short* __restrict__ WtT,
    unsigned short* __restrict__ WtB,
    void* __restrict__ outv, long long moff, long long soff, long long voff)
{
    __shared__ __align__(16) unsigned char smem[12544];
    int blk = blockIdx.x, tid = threadIdx.x;
    int isf = probe_isf(seq);
    if (blk < PREP_GATHER) {
        if (blk < B_ * E_) {
            int b = blk / E_, e = blk % E_;
            int i0 = epos[(b * E_ + e) * K_ + 0] + 1;
            int i1 = epos[(b * E_ + e) * K_ + 1] + 1;
            size_t r0 = ((size_t)b * C_ + i0) * D_;
            size_t r1 = ((size_t)b * C_ + i1) * D_;
            size_t m0 = (size_t)moff + ((size_t)(b * E_ * K_) + 2 * e) * D_;
            size_t m1 = m0 + D_;
            float* eh = enth + (size_t)(b * E_ + e) * DNT_;
            for (int d = tid; d < D_; d += 256) {
                float a = ld_in(seq, r0 + d, isf);
                float c = ld_in(seq, r1 + d, isf);
                st_out(outv, m0 + d, a, isf);
                st_out(outv, m1 + d, c, isf);
                float mx = fmaxf(a, c);
                eh[d] = mx + logf(expf(a - mx) + expf(c - mx));
            }
            size_t nt0 = (size_t)(b * E_ + e) * NT_;
            for (int j = tid; j < NT_; j += 256) eh[D_ + j] = ld_in(ntype, nt0 + j, isf);
        } else if (blk < B_ * E_ + B_ * S_) {
            int t = blk - B_ * E_; int b = t / S_, s = t % S_;
            int i = spos[b * S_ + s] + 1;
            size_t r = ((size_t)b * C_ + i) * D_;
            size_t o = (size_t)soff + (size_t)(b * S_ + s) * D_;
            for (int d = tid; d < D_; d += 256) st_out(outv, o + d, ld_in(seq, r + d, isf), isf);
        } else {
            int t = blk - B_ * E_ - B_ * S_; int b = t / V_, v = t % V_;
            int i = vpos[b * V_ + v] + 1;
            size_t r = ((size_t)b * C_ + i) * D_;
            size_t o = (size_t)voff + (size_t)(b * V_ + v) * D_;
            for (int d = tid; d < D_; d += 256) st_out(outv, o + d, ld_in(seq, r + d, isf), isf);
        }
    } else if (blk < PREP_EATT) {
        int t = blk - PREP_GATHER;
        int b = t / (E_ * H_); int r = t % (E_ * H_); int e = r / H_; int h = r % H_;
        int i0 = epos[(b * E_ + e) * K_ + 0] + 1;
        int i1 = epos[(b * E_ + e) * K_ + 1] + 1;
        size_t a0 = (((size_t)b * H_ + h) * C_ + i0) * C_;
        size_t a1 = (((size_t)b * H_ + h) * C_ + i1) * C_;
        unsigned short* o = e_att + (((size_t)(b * E_ + e)) * H_ + h) * C_;
        for (int c = tid; c < C_; c += 256)
            o[c] = f2b(0.5f * (ld_in(att, a0 + c, isf) + ld_in(att, a1 + c, isf)));
    } else if (blk < PREP_TSEQ) {
        int t = blk - PREP_EATT;                 // b*192 + ct*12 + dt
        int b = t / 192; int r = t % 192; int ct = r / 12; int dt = r % 12;
        typedef unsigned short row65[65];
        row65* tile = (row65*)smem;
        for (int idx = tid; idx < 4096; idx += 256) {
            int cc = idx >> 6, dd = idx & 63;
            tile[cc][dd] = f2b(ld_in(seq, ((size_t)b * C_ + ct * 64 + cc) * D_ + dt * 64 + dd, isf));
        }
        __syncthreads();
        for (int idx = tid; idx < 4096; idx += 256) {
            int dd = idx >> 6, cc = idx & 63;
            seqT[((size_t)b * D_ + dt * 64 + dd) * C_ + ct * 64 + cc] = tile[cc][dd];
        }
    } else if (blk < PREP_TW) {
        int t = blk - PREP_TSEQ;                 // mat*336 + kt*12 + nt
        int mat = t / 336; int r = t % 336; int kt = r / 12; int nt = r % 12;
        const void* in = mat ? Wt_ : Wh;
        unsigned short* out = mat ? WtT : WtH;
        typedef unsigned short row65[65];
        row65* tile = (row65*)smem;
        for (int idx = tid; idx < 4096; idx += 256) {
            int kk = idx >> 6, nn = idx & 63;
            tile[kk][nn] = f2b(ld_in(in, ((size_t)kt * 64 + kk) * EMB_ + nt * 64 + nn, isf));
        }
        __syncthreads();
        for (int idx = tid; idx < 4096; idx += 256) {
            int nn = idx >> 6, kk = idx & 63;
            out[((size_t)nt * 64 + nn) * KHT_ + kt * 64 + kk] = tile[kk][nn];
        }
    } else {
        int t = blk - PREP_TW;                   // 64 k-cols per block
        int k0 = t << 6;
        unsigned short* raw = (unsigned short*)smem;   // [64*97]
        for (int idx = tid; idx < 64 * NL_; idx += 256)
            raw[idx] = f2b(ld_in(Wb, (size_t)k0 * NL_ + idx, isf));
        __syncthreads();
        int kk = tid & 63, nq = tid >> 6;              // 4 quarters x 32 n
        for (int i = 0; i < 32; i++) {
            int n = nq * 32 + i;
            unsigned short v = (n < NL_) ? raw[kk * NL_ + n] : (unsigned short)0;
            WtB[(size_t)n * KBIL_ + k0 + kk] = v;
        }
    }
}

// ---------------------------------------------------------------------------
// K2 fused mid: [0,2048) htatt, [2048,4096) xbuild, [4096,4352) zero logitsF
__global__ __launch_bounds__(256) void k_mid(
    const unsigned short* __restrict__ e_att, const float* __restrict__ enth,
    const int* __restrict__ hts,
    unsigned short* __restrict__ htb,
    unsigned short* __restrict__ Xh, unsigned short* __restrict__ Xt,
    float* __restrict__ logitsF)
{
    __shared__ float red[4];
    int blk = blockIdx.x, tid = threadIdx.x;
    if (blk < B_ * P_) {
        int b = blk >> 9;
        int he = hts[blk * 2 + 0], te = hts[blk * 2 + 1];
        const unsigned short* ph = e_att + (size_t)(b * E_ + he) * H_ * C_;
        const unsigned short* pt = e_att + (size_t)(b * E_ + te) * H_ * C_;
        float v[4]; float ls = 0.f;
        for (int ci = 0; ci < 4; ci++) {
            int c = tid + (ci << 8);
            float acc = 0.f;
#pragma unroll
            for (int h = 0; h < H_; h++) acc += b2f(ph[h * C_ + c]) * b2f(pt[h * C_ + c]);
            acc *= (1.0f / (float)H_);
            v[ci] = acc; ls += acc;
        }
        for (int off = 32; off > 0; off >>= 1) ls += __shfl_down(ls, off, 64);
        if ((tid & 63) == 0) red[tid >> 6] = ls;
        __syncthreads();
        float inv = 1.0f / (red[0] + red[1] + red[2] + red[3] + 1e-5f);
        for (int ci = 0; ci < 4; ci++)
            htb[((size_t)blk << 10) + tid + (ci << 8)] = f2b(v[ci] * inv);
    } else if (blk < 2 * B_ * P_) {
        int m = blk - B_ * P_; int b = m >> 9;
        int eh = hts[m * 2 + 0], et = hts[m * 2 + 1];
        const float* sh = enth + (size_t)(b * E_ + eh) * DNT_;
        const float* st = enth + (size_t)(b * E_ + et) * DNT_;
        for (int k = tid; k < DNT_; k += 256) {
            Xh[(size_t)m * KHT_ + k] = f2b(sh[k]);
            Xt[(size_t)m * KHT_ + k] = f2b(st[k]);
        }
    } else {
        int t = blk - 2 * B_ * P_;               // 256 blocks zero 1 MB
        ((float4*)logitsF)[(size_t)t * 256 + tid] = make_float4(0.f, 0.f, 0.f, 0.f);
    }
}

// ---------------------------------------------------------------------------
// bf16 MFMA GEMM, 64x64 tile, 4 waves 2x2, K-step 32, LDS staging (coalesced),
// register prefetch. (R5's LDS-free variant thrashed L2 -- reverted.)
// zmode 0 (rs): z = batch; epilogue writes bf16 into Xh/Xt cols DNT_+n.
// zmode 1 (ht): z = mat (0=head,1=tail); epilogue bf16 tanh(acc+bias) -> oY.
__global__ __launch_bounds__(256) void k_gemm(
    const unsigned short* __restrict__ A0, const unsigned short* __restrict__ A1,
    const unsigned short* __restrict__ B0, const unsigned short* __restrict__ B1,
    long long lda, long long ldb, long long sAz, long long sBz,
    int nsteps, int zmode,
    const void* __restrict__ bias0, const void* __restrict__ bias1,
    unsigned short* __restrict__ oY0, unsigned short* __restrict__ oY1,
    unsigned short* __restrict__ oX1, unsigned short* __restrict__ oX2,
    const void* __restrict__ seq)
{
    int n0 = blockIdx.x * 64, m0 = blockIdx.y * 64, z = blockIdx.z;
    const unsigned short* Ab; const unsigned short* Bb;
    unsigned short* oY = nullptr; const void* bias = nullptr;
    if (zmode == 0) {
        Ab = A0 + (size_t)z * sAz; Bb = B0 + (size_t)z * sBz;
    } else {
        Ab = z ? A1 : A0; Bb = z ? B1 : B0;
        oY = z ? oY1 : oY0; bias = z ? bias1 : bias0;
    }
    __shared__ __align__(16) unsigned short a_lds[64][40];
    __shared__ __align__(16) unsigned short b_lds[64][40];
    int tid = threadIdx.x, lane = tid & 63, w = tid >> 6;
    int wm = (w >> 1) * 32, wn = (w & 1) * 32, q = lane >> 4, l15 = lane & 15;
    f32x4 acc00 = {0.f,0.f,0.f,0.f}, acc01 = acc00, acc10 = acc00, acc11 = acc00;
    int srow = tid >> 2, sch = (tid & 3) * 8;
    const unsigned short* pa = Ab + (size_t)(m0 + srow) * lda + sch;
    const unsigned short* pb = Bb + (size_t)(n0 + srow) * ldb + sch;
    int4 ra = *(const int4*)pa;
    int4 rb = *(const int4*)pb;
    for (int ks = 0; ks < nsteps; ks++) {
        __syncthreads();
        *(int4*)&a_lds[srow][sch] = ra;
        *(int4*)&b_lds[srow][sch] = rb;
        __syncthreads();
        if (ks + 1 < nsteps) {
            ra = *(const int4*)(pa + (size_t)(ks + 1) * 32);
            rb = *(const int4*)(pb + (size_t)(ks + 1) * 32);
        }
        bf16x8 a0 = *(const bf16x8*)&a_lds[wm + l15][q * 8];
        bf16x8 a1 = *(const bf16x8*)&a_lds[wm + 16 + l15][q * 8];
        bf16x8 b0 = *(const bf16x8*)&b_lds[wn + l15][q * 8];
        bf16x8 b1 = *(const bf16x8*)&b_lds[wn + 16 + l15][q * 8];
        acc00 = __builtin_amdgcn_mfma_f32_16x16x32_bf16(a0, b0, acc00, 0, 0, 0);
        acc01 = __builtin_amdgcn_mfma_f32_16x16x32_bf16(a0, b1, acc01, 0, 0, 0);
        acc10 = __builtin_amdgcn_mfma_f32_16x16x32_bf16(a1, b0, acc10, 0, 0, 0);
        acc11 = __builtin_amdgcn_mfma_f32_16x16x32_bf16(a1, b1, acc11, 0, 0, 0);
    }
    f32x4 accs[2][2] = {{acc00, acc01}, {acc10, acc11}};
    int isf = (zmode == 1) ? probe_isf(seq) : 0;
#pragma unroll
    for (int mt = 0; mt < 2; mt++)
#pragma unroll
        for (int nt = 0; nt < 2; nt++) {
            int gmb = m0 + wm + mt * 16 + q * 4;
            int gn  = n0 + wn + nt * 16 + l15;
            if (zmode == 0) {
#pragma unroll
                for (int r = 0; r < 4; r++) {
                    unsigned short v = f2b(accs[mt][nt][r]);
                    size_t o = (size_t)(z * P_ + gmb + r) * KHT_ + DNT_ + gn;
                    oX1[o] = v; oX2[o] = v;
                }
            } else {
                float bv = ld_in(bias, gn, isf);
#pragma unroll
                for (int r = 0; r < 4; r++)
                    oY[(size_t)(gmb + r) * EMB_ + gn] = f2b(tanhf(accs[mt][nt][r] + bv));
            }
        }
}

// ---------------------------------------------------------------------------
// Grouped bilinear via MFMA, K split over groups (grid.y = g), atomic f32 acc.
// hs/ts arrive pre-tanh'd in bf16. Depth-2 B-fragment prefetch.
__global__ __launch_bounds__(256) void k_bil(
    const unsigned short* __restrict__ hsB, const unsigned short* __restrict__ tsB,
    const unsigned short* __restrict__ WtB, float* __restrict__ logitsF)
{
    int m0 = blockIdx.x * 32;
    int g  = blockIdx.y;
    int tid = threadIdx.x, lane = tid & 63, w = tid >> 6;
    int q = lane >> 4, l15 = lane & 15;
    __shared__ __align__(16) unsigned short hsl[32][80];   // 160 B rows (16B-aligned)
    __shared__ __align__(16) unsigned short tsl[32][80];
    for (int idx = tid; idx < 512; idx += 256) {
        int m = idx >> 4, j4 = (idx & 15) * 4;
        *(ushort4*)&hsl[m][j4] = *(const ushort4*)&hsB[(size_t)(m0 + m) * EMB_ + g * 64 + j4];
        *(ushort4*)&tsl[m][j4] = *(const ushort4*)&tsB[(size_t)(m0 + m) * EMB_ + g * 64 + j4];
    }
    __syncthreads();

    const unsigned short* pB0 = WtB + (size_t)(w * 16 + l15) * KBIL_ + g * 4096 + q * 8;
    const unsigned short* pB1 = pB0 + (size_t)64 * KBIL_;
    bf16x8 rb0[2], rb1[2];
    rb0[0] = *(const bf16x8*)(pB0);      rb1[0] = *(const bf16x8*)(pB1);
    rb0[1] = *(const bf16x8*)(pB0 + 32); rb1[1] = *(const bf16x8*)(pB1 + 32);
    f32x4 acc00 = {0.f,0.f,0.f,0.f}, acc01 = acc00, acc10 = acc00, acc11 = acc00;

#pragma unroll 2
    for (int kk = 0; kk < 128; kk++) {
        int sl = kk & 1;
        bf16x8 bw0 = rb0[sl], bw1 = rb1[sl];
        if (kk + 2 < 128) {
            rb0[sl] = *(const bf16x8*)(pB0 + (size_t)(kk + 2) * 32);
            rb1[sl] = *(const bf16x8*)(pB1 + (size_t)(kk + 2) * 32);
        }
        int i = kk >> 1, h = kk & 1;
        float ha0 = b2f(hsl[l15][i]);
        float ha1 = b2f(hsl[16 + l15][i]);
        bf16x8 t0 = *(const bf16x8*)&tsl[l15][h * 32 + q * 8];
        bf16x8 t1 = *(const bf16x8*)&tsl[16 + l15][h * 32 + q * 8];
        bf16x8 af0, af1;
#pragma unroll
        for (int j = 0; j < 8; j++) {
            af0[j] = (__bf16)(ha0 * (float)t0[j]);
            af1[j] = (__bf16)(ha1 * (float)t1[j]);
        }
        acc00 = __builtin_amdgcn_mfma_f32_16x16x32_bf16(af0, bw0, acc00, 0, 0, 0);
        acc01 = __builtin_amdgcn_mfma_f32_16x16x32_bf16(af0, bw1, acc01, 0, 0, 0);
        acc10 = __builtin_amdgcn_mfma_f32_16x16x32_bf16(af1, bw0, acc10, 0, 0, 0);
        acc11 = __builtin_amdgcn_mfma_f32_16x16x32_bf16(af1, bw1, acc11, 0, 0, 0);
    }
#pragma unroll
    for (int r = 0; r < 4; r++) {
        atomicAdd(&logitsF[(size_t)(m0 + q * 4 + r) * NPAD_ + w * 16 + l15],           acc00[r]);
        atomicAdd(&logitsF[(size_t)(m0 + q * 4 + r) * NPAD_ + w * 16 + 64 + l15],      acc01[r]);
        atomicAdd(&logitsF[(size_t)(m0 + 16 + q * 4 + r) * NPAD_ + w * 16 + l15],      acc10[r]);
        atomicAdd(&logitsF[(size_t)(m0 + 16 + q * 4 + r) * NPAD_ + w * 16 + 64 + l15], acc11[r]);
    }
}

// ---------------------------------------------------------------------------
// final: logits out with bias, n<97
__global__ __launch_bounds__(256) void k_fin(
    const float* __restrict__ logitsF, const void* __restrict__ b_bil,
    void* __restrict__ outv, const void* __restrict__ seq)
{
    int isf = probe_isf(seq);
    int idx = blockIdx.x * 256 + threadIdx.x;
    if (idx >= B_ * P_ * NL_) return;
    int m = idx / NL_, n = idx % NL_;
    st_out(outv, idx, logitsF[(size_t)m * NPAD_ + n] + ld_in(b_bil, n, isf), isf);
}

// ---------------------------------------------------------------------------
extern "C" void kernel_launch(void* const* d_in, const int* in_sizes, int n_in,
                              void* d_out, int out_size, void* d_ws, size_t ws_size,
                              hipStream_t stream)
{
    const void* seq    = d_in[0];
    const void* att    = d_in[1];
    const int*  epos   = (const int*)d_in[2];
    const int*  spos   = (const int*)d_in[3];
    const int*  vpos   = (const int*)d_in[4];
    const int*  hts    = (const int*)d_in[5];
    const void* ntype  = d_in[6];
    const void* W_head = d_in[7];
    const void* b_head = d_in[8];
    const void* W_tail = d_in[9];
    const void* b_tail = d_in[10];
    const void* W_bil  = d_in[11];
    const void* b_bil  = d_in[12];

    // output element offsets (dtype-agnostic)
    long long mention_off = (long long)B_ * P_ * NL_;
    long long sent_off    = mention_off + (long long)B_ * E_ * K_ * D_;
    long long virt_off    = sent_off + (long long)B_ * S_ * D_;

    // workspace carve (~50 MB)
    char* p = (char*)d_ws;
    auto alloc = [&](size_t bytes) { void* r = (void*)p; p += (bytes + 255) & ~(size_t)255; return r; };
    unsigned short* e_att   = (unsigned short*)alloc((size_t)B_ * E_ * H_ * C_ * 2);
    unsigned short* htb     = (unsigned short*)alloc((size_t)B_ * P_ * C_ * 2);
    unsigned short* seqT    = (unsigned short*)alloc((size_t)B_ * D_ * C_ * 2);
    unsigned short* WtH     = (unsigned short*)alloc((size_t)EMB_ * KHT_ * 2);
    unsigned short* WtT     = (unsigned short*)alloc((size_t)EMB_ * KHT_ * 2);
    unsigned short* WtB     = (unsigned short*)alloc((size_t)NPAD_ * KBIL_ * 2);
    unsigned short* Xh      = (unsigned short*)alloc((size_t)B_ * P_ * KHT_ * 2);
    unsigned short* Xt      = (unsigned short*)alloc((size_t)B_ * P_ * KHT_ * 2);
    unsigned short* hsB     = (unsigned short*)alloc((size_t)B_ * P_ * EMB_ * 2);
    unsigned short* tsB     = (unsigned short*)alloc((size_t)B_ * P_ * EMB_ * 2);
    float*          logitsF = (float*)alloc((size_t)B_ * P_ * NPAD_ * 4);
    float*          enth    = (float*)alloc((size_t)B_ * E_ * DNT_ * 4);

    dim3 blk(256);
    k_prep<<<PREP_TBIL, blk, 0, stream>>>(
        seq, att, epos, spos, vpos, ntype, W_head, W_tail, W_bil,
        enth, e_att, seqT, WtH, WtT, WtB,
        d_out, mention_off, sent_off, virt_off);
    k_mid<<<2 * B_ * P_ + 256, blk, 0, stream>>>(e_att, enth, hts, htb, Xh, Xt, logitsF);
    // rs GEMM: per batch [512 x 1024] @ [1024 x 768]^T -> X cols 1024..1791
    k_gemm<<<dim3(EMB_ / 64, P_ / 64, B_), blk, 0, stream>>>(
        htb, nullptr, seqT, nullptr, C_, C_,
        (long long)P_ * C_, (long long)D_ * C_, C_ / 32, 0,
        nullptr, nullptr, nullptr, nullptr, Xh, Xt, seq);
    // fused head+tail: [2048 x 1792] @ [1792 x 768]^T, tanh+bias -> bf16 hsB/tsB
    k_gemm<<<dim3(EMB_ / 64, (B_ * P_) / 64, 2), blk, 0, stream>>>(
        Xh, Xt, WtH, WtT, KHT_, KHT_, 0, 0, KHT_ / 32, 1,
        b_head, b_tail, hsB, tsB, nullptr, nullptr, seq);
    k_bil<<<dim3((B_ * P_) / 32, 12, 1), blk, 0, stream>>>(hsB, tsB, WtB, logitsF);
    k_fin<<<(B_ * P_ * NL_ + 255) / 256, blk, 0, stream>>>(logitsF, b_bil, d_out, seq);
}